// Round 14
// baseline (46.498 us; speedup 1.0000x reference)
//
#include <hip/hip_runtime.h>
#include <hip/hip_bf16.h>

#define NNODES 50000
#define NEDGES 200000
#define WCT_ROW 552                      // f16 units; 1104B padded row
#define WCT_BYTES (32 * WCT_ROW * 2)     // 35328
#define HROW 40                          // f16 units; 80B row
#define TILE_EDGES 64
#define EDGES_PER_BLOCK 256              // 4 tiles
#define WORK_BLOCKS ((NEDGES + EDGES_PER_BLOCK - 1) / EDGES_PER_BLOCK) // 782
#define DROW 33                          // dtile row stride (floats)

// workspace layout (bytes, 16B-aligned)
#define MSG_OFF   0                      // f32[200000*32] natural layout msg[e][32]
#define HEAD_OFF  25600000               // u32[50000]
#define NEXT_OFF  25800000               // u32[200000]
#define WCT_OFF   26600000               // f16[32*552]

using f32x4 = __attribute__((ext_vector_type(4))) float;
using f16x2 = __attribute__((ext_vector_type(2))) _Float16;
using f16x4 = __attribute__((ext_vector_type(4))) _Float16;
using f16x8 = __attribute__((ext_vector_type(8))) _Float16;

__device__ __forceinline__ f16x2 pkrtz(float a, float b) {
    return __builtin_bit_cast(f16x2, __builtin_amdgcn_cvt_pkrtz(a, b));
}

__device__ __forceinline__ void gload_lds16(const void* g, void* l) {
    __builtin_amdgcn_global_load_lds(
        (const __attribute__((address_space(1))) unsigned int*)g,
        (__attribute__((address_space(3))) unsigned int*)l, 16, 0, 0);
}

// ---- D1: wct build (blocks 0..68) + head init (blocks 69..) ----
#define WCT_BLKS 69
__global__ void init_kernel(const float* __restrict__ W_edge,
                            const float* __restrict__ b_edge,
                            _Float16* __restrict__ wct,
                            unsigned* __restrict__ head) {
    int b = blockIdx.x;
    if (b < WCT_BLKS) {
        int gid = b * 256 + threadIdx.x;
        if (gid >= 32 * WCT_ROW) return;
        int n = gid / WCT_ROW;
        int c = gid - n * WCT_ROW;
        float v = 0.0f;
        if (c < 512)      v = W_edge[(c & 15) * 1024 + (c >> 4) * 32 + n];
        else if (c < 544) v = b_edge[(c - 512) * 32 + n];
        wct[gid] = (_Float16)v;
    } else {
        int gid = (b - WCT_BLKS) * 256 + threadIdx.x;
        if (gid < NNODES) head[gid] = 0xFFFFFFFFu;
    }
}

// ---- D2: 4 tiles/block; wct staged once; chain scatter fused; no per-tile barrier ----
__global__ __launch_bounds__(256, 3) void work_kernel(
    const float* __restrict__ feat, const float* __restrict__ efeat,
    const int* __restrict__ src, const int* __restrict__ dst,
    const _Float16* __restrict__ wct_g,
    float4* __restrict__ msg4, unsigned* __restrict__ head,
    unsigned* __restrict__ next) {

    __shared__ __align__(16) unsigned short wct_lds[32 * WCT_ROW]; // 35328 B
    __shared__ __align__(16) unsigned short h_lds[TILE_EDGES * HROW]; // 5120 B
    __shared__ __align__(16) float dtile[TILE_EDGES * DROW];       // 8448 B

    const int t = threadIdx.x;
    const int lane = t & 63;
    const int wave = t >> 6;
    const int bbase = blockIdx.x * EDGES_PER_BLOCK;

    // Stage WcT global->LDS async ONCE (linear dest, 16B/lane)
    {
        const char* gsrc = (const char*)wct_g;
        char* lbase = (char*)wct_lds;
        #pragma unroll
        for (int c = 0; c < 9; ++c) {
            int chunk = wave + c * 4;
            if (chunk < 35) {
                int boff = (chunk << 10) + lane * 16;
                if (boff < WCT_BYTES) gload_lds16(gsrc + boff, lbase + boff);
            }
        }
    }

    // Chain-scatter all 256 edges of this block (1 atomicExch/thread)
    {
        int e = bbase + t;
        if (e < NEDGES)
            next[e] = atomicExch(&head[dst[e]], (unsigned)e);
    }

    __syncthreads();   // drains wct global_load_lds (cross-wave dependency)

    const int r16 = lane & 15;
    const int g   = lane >> 4;
    const int wbase = wave * 16;

    const _Float16* brow0 = (const _Float16*)wct_lds + r16 * WCT_ROW;
    const _Float16* brow1 = (const _Float16*)wct_lds + (16 + r16) * WCT_ROW;

    #pragma unroll
    for (int tt = 0; tt < 4; ++tt) {
        const int ebase = bbase + tt * TILE_EDGES;
        if (ebase >= NEDGES) break;

        // Stage gathered h (f32 -> f16): wave-private rows (et = t>>2)
        {
            int et = t >> 2, p = t & 3;
            int se = src[ebase + et];
            const float* fp = feat + se * 32 + p * 8;
            float4 a = *(const float4*)fp;
            float4 b = *(const float4*)(fp + 4);
            uint4 hp;
            hp.x = __builtin_bit_cast(unsigned int, pkrtz(a.x, a.y));
            hp.y = __builtin_bit_cast(unsigned int, pkrtz(a.z, a.w));
            hp.z = __builtin_bit_cast(unsigned int, pkrtz(b.x, b.y));
            hp.w = __builtin_bit_cast(unsigned int, pkrtz(b.z, b.w));
            *(uint4*)(void*)(h_lds + et * HROW + p * 8) = hp;
        }

        const int eg = ebase + wbase + r16;
        const float* efp = efeat + eg * 16 + (g & 1) * 8;
        float4 e0 = *(const float4*)efp;
        float4 e1 = *(const float4*)(efp + 4);
        f16x2 ef2[4] = { pkrtz(e0.x, e0.y), pkrtz(e0.z, e0.w),
                         pkrtz(e1.x, e1.y), pkrtz(e1.z, e1.w) };

        // same-wave ds_write -> ds_read fence (rule #18)
        asm volatile("s_waitcnt lgkmcnt(0)" ::: "memory");
        __builtin_amdgcn_sched_barrier(0);

        // h row -> regs; per-s broadcast half2 of h[2s + (g>>1)]
        unsigned int hbc[16];
        f16x8 af_bias;
        {
            const uint4* hrow = (const uint4*)(void*)(h_lds + (wbase + r16) * HROW);
            unsigned int hw[16];
            #pragma unroll
            for (int q = 0; q < 4; ++q) {
                uint4 v = hrow[q];
                hw[q*4+0] = v.x; hw[q*4+1] = v.y; hw[q*4+2] = v.z; hw[q*4+3] = v.w;
            }
            const bool hi = (g >> 1) & 1;
            #pragma unroll
            for (int s = 0; s < 16; ++s) {
                unsigned int x = hi ? (hw[s] >> 16) : (hw[s] & 0xffffu);
                hbc[s] = x | (x << 16);
            }
            af_bias = *(const f16x8*)(void*)((const _Float16*)h_lds + (wbase + r16) * HROW + g * 8);
        }

        f32x4 acc0 = {0.f, 0.f, 0.f, 0.f};
        f32x4 acc1 = {0.f, 0.f, 0.f, 0.f};

        // X[e,c]=h[i]*ef[kk], c=32s+8g+j => i=2s+(g>>1), kk=(g&1)*8+j
        #pragma unroll
        for (int s = 0; s < 16; ++s) {
            const int koff = s * 32 + g * 8;
            f16x8 b0 = *(const f16x8*)(brow0 + koff);
            f16x8 b1 = *(const f16x8*)(brow1 + koff);
            f16x2 hb = __builtin_bit_cast(f16x2, hbc[s]);
            f16x2 p0 = hb * ef2[0], p1 = hb * ef2[1], p2 = hb * ef2[2], p3 = hb * ef2[3];
            f16x4 lo  = __builtin_shufflevector(p0, p1, 0, 1, 2, 3);
            f16x4 hi4 = __builtin_shufflevector(p2, p3, 0, 1, 2, 3);
            f16x8 af  = __builtin_shufflevector(lo, hi4, 0, 1, 2, 3, 4, 5, 6, 7);
            acc0 = __builtin_amdgcn_mfma_f32_16x16x32_f16(af, b0, acc0, 0, 0, 0);
            acc1 = __builtin_amdgcn_mfma_f32_16x16x32_f16(af, b1, acc1, 0, 0, 0);
        }
        {   // bias-extension k-step: X[e,512+i]=h[i]
            const int koff = 512 + g * 8;
            f16x8 b0 = *(const f16x8*)(brow0 + koff);
            f16x8 b1 = *(const f16x8*)(brow1 + koff);
            acc0 = __builtin_amdgcn_mfma_f32_16x16x32_f16(af_bias, b0, acc0, 0, 0, 0);
            acc1 = __builtin_amdgcn_mfma_f32_16x16x32_f16(af_bias, b1, acc1, 0, 0, 0);
        }

        // D (m89): rows wbase+4g+r (wave-private), cols r16 / 16+r16
        {
            const int browD = wbase + g * 4;
            #pragma unroll
            for (int r = 0; r < 4; ++r) {
                dtile[(browD + r) * DROW + r16]      = acc0[r];
                dtile[(browD + r) * DROW + 16 + r16] = acc1[r];
            }
        }
        asm volatile("s_waitcnt lgkmcnt(0)" ::: "memory");
        __builtin_amdgcn_sched_barrier(0);

        // Dense natural-layout msg store (wave-private dtile rows):
        // lane l -> rows wbase+(l>>3) and +8, floats (l&7)*4..+3
        {
            const int rA = wbase + (lane >> 3);
            const int cA = (lane & 7) * 4;
            float4 vA = *(const float4*)(dtile + rA * DROW + cA);
            float4 vB = *(const float4*)(dtile + (rA + 8) * DROW + cA);
            float4* mp = msg4 + (size_t)ebase * 8 + wave * 128;
            mp[lane]      = vA;   // msg4[e*8 + q], e = ebase+16w+(l>>3), q = l&7
            mp[64 + lane] = vB;
        }
    }
}

// ---- D3: pull — 8 lanes per node walk the chain; coalesced 128B/edge reads ----
__global__ __launch_bounds__(256) void pull_kernel(
    const float4* __restrict__ msg4, const unsigned* __restrict__ head,
    const unsigned* __restrict__ next, const float* __restrict__ bias,
    float* __restrict__ out) {

    int gid = blockIdx.x * 256 + threadIdx.x;
    if (gid >= NNODES * 8) return;
    int n = gid >> 3, Q = gid & 7;

    float4 s = {0.f, 0.f, 0.f, 0.f};
    float degf = 0.0f;

    unsigned e = head[n];
    while (e != 0xFFFFFFFFu) {
        float4 m = msg4[(size_t)e * 8 + Q];
        s.x += m.x; s.y += m.y; s.z += m.z; s.w += m.w;
        degf += 1.0f;
        e = next[e];
    }

    float inv = 1.0f / fmaxf(degf, 1.0f);
    float4 b = ((const float4*)bias)[Q];
    float4 o = { s.x * inv + b.x, s.y * inv + b.y, s.z * inv + b.z, s.w * inv + b.w };
    *(float4*)(out + n * 32 + Q * 4) = o;
}

extern "C" void kernel_launch(void* const* d_in, const int* in_sizes, int n_in,
                              void* d_out, int out_size, void* d_ws, size_t ws_size,
                              hipStream_t stream) {
    const float* feat   = (const float*)d_in[0];
    const float* efeat  = (const float*)d_in[1];
    const int*   src    = (const int*)d_in[2];
    const int*   dst    = (const int*)d_in[3];
    const float* W_edge = (const float*)d_in[4];
    const float* b_edge = (const float*)d_in[5];
    const float* bias   = (const float*)d_in[6];

    char* ws = (char*)d_ws;
    float4*   msg4 = (float4*)(ws + MSG_OFF);
    unsigned* head = (unsigned*)(ws + HEAD_OFF);
    unsigned* next = (unsigned*)(ws + NEXT_OFF);
    _Float16* wct  = (_Float16*)(ws + WCT_OFF);
    float*    out  = (float*)d_out;

    init_kernel<<<WCT_BLKS + (NNODES + 255) / 256, 256, 0, stream>>>(
        W_edge, b_edge, wct, head);
    work_kernel<<<WORK_BLOCKS, 256, 0, stream>>>(
        feat, efeat, src, dst, wct, msg4, head, next);
    pull_kernel<<<(NNODES * 8 + 255) / 256, 256, 0, stream>>>(
        msg4, head, next, bias, out);
}

// Round 15
// 43.154 us; speedup vs baseline: 1.0775x; 1.0775x over previous
//
#include <hip/hip_runtime.h>
#include <hip/hip_bf16.h>

#define NNODES 50000
#define NEDGES 200000
#define WCT_ROW 552                      // f16 units; 1104B padded row
#define WCT_BYTES (32 * WCT_ROW * 2)     // 35328
#define HROW 40                          // f16 units; 80B row
#define TILE_EDGES 64
#define NTILES (NEDGES / TILE_EDGES)     // 3125
#define CHAIN_BLKS ((NEDGES + 255) / 256) // 782
#define DROW 33                          // dtile row stride (floats)

// workspace layout (bytes, 16B-aligned)
#define MSG_OFF   0                      // f16[200000*32] natural layout = 12,800,000
#define HEAD_OFF  12800000               // u32[50000]
#define NEXT_OFF  13000000               // u32[200000]
#define WCT_OFF   13800000               // f16[32*552]

using f32x4 = __attribute__((ext_vector_type(4))) float;
using f16x2 = __attribute__((ext_vector_type(2))) _Float16;
using f16x4 = __attribute__((ext_vector_type(4))) _Float16;
using f16x8 = __attribute__((ext_vector_type(8))) _Float16;

__device__ __forceinline__ f16x2 pkrtz(float a, float b) {
    return __builtin_bit_cast(f16x2, __builtin_amdgcn_cvt_pkrtz(a, b));
}

__device__ __forceinline__ void gload_lds16(const void* g, void* l) {
    __builtin_amdgcn_global_load_lds(
        (const __attribute__((address_space(1))) unsigned int*)g,
        (__attribute__((address_space(3))) unsigned int*)l, 16, 0, 0);
}

// ---- D1: wct build (blocks 0..68) + head init (blocks 69..) ----
#define WCT_BLKS 69
__global__ void init_kernel(const float* __restrict__ W_edge,
                            const float* __restrict__ b_edge,
                            _Float16* __restrict__ wct,
                            unsigned* __restrict__ head) {
    int b = blockIdx.x;
    if (b < WCT_BLKS) {
        int gid = b * 256 + threadIdx.x;
        if (gid >= 32 * WCT_ROW) return;
        int n = gid / WCT_ROW;
        int c = gid - n * WCT_ROW;
        float v = 0.0f;
        if (c < 512)      v = W_edge[(c & 15) * 1024 + (c >> 4) * 32 + n];
        else if (c < 544) v = b_edge[(c - 512) * 32 + n];
        wct[gid] = (_Float16)v;
    } else {
        int gid = (b - WCT_BLKS) * 256 + threadIdx.x;
        if (gid < NNODES) head[gid] = 0xFFFFFFFFu;
    }
}

// ---- D2: GEMM blocks (0..3124) -> f16 msg (natural layout); chain blocks scatter ----
__global__ __launch_bounds__(256, 3) void work_kernel(
    const float* __restrict__ feat, const float* __restrict__ efeat,
    const int* __restrict__ src, const int* __restrict__ dst,
    const _Float16* __restrict__ wct_g,
    uint4* __restrict__ msgq, unsigned* __restrict__ head,
    unsigned* __restrict__ next) {

    __shared__ __align__(16) unsigned short wct_lds[32 * WCT_ROW]; // 35328 B
    __shared__ __align__(16) unsigned short h_lds[TILE_EDGES * HROW]; // 5120 B
    __shared__ __align__(16) float dtile[TILE_EDGES * DROW];       // 8448 B

    const int t = threadIdx.x;

    if (blockIdx.x >= NTILES) {
        // chain-scatter: per-dst linked list via atomicExch (200K atomics)
        int e = (blockIdx.x - NTILES) * 256 + t;
        if (e < NEDGES)
            next[e] = atomicExch(&head[dst[e]], (unsigned)e);
        return;
    }

    const int lane = t & 63;
    const int wave = t >> 6;
    const int ebase = blockIdx.x * TILE_EDGES;

    // Stage WcT global->LDS async (linear dest, 16B/lane)
    {
        const char* gsrc = (const char*)wct_g;
        char* lbase = (char*)wct_lds;
        #pragma unroll
        for (int c = 0; c < 9; ++c) {
            int chunk = wave + c * 4;
            if (chunk < 35) {
                int boff = (chunk << 10) + lane * 16;
                if (boff < WCT_BYTES) gload_lds16(gsrc + boff, lbase + boff);
            }
        }
    }

    // Stage gathered h (f32 -> f16): wave-private rows (et = t>>2)
    {
        int et = t >> 2, p = t & 3;
        int se = src[ebase + et];
        const float* fp = feat + se * 32 + p * 8;
        float4 a = *(const float4*)fp;
        float4 b = *(const float4*)(fp + 4);
        uint4 hp;
        hp.x = __builtin_bit_cast(unsigned int, pkrtz(a.x, a.y));
        hp.y = __builtin_bit_cast(unsigned int, pkrtz(a.z, a.w));
        hp.z = __builtin_bit_cast(unsigned int, pkrtz(b.x, b.y));
        hp.w = __builtin_bit_cast(unsigned int, pkrtz(b.z, b.w));
        *(uint4*)(void*)(h_lds + et * HROW + p * 8) = hp;
    }

    const int r16 = lane & 15;
    const int g   = lane >> 4;
    const int wbase = wave * 16;
    const int eg = ebase + wbase + r16;

    // ef fragment (independent of LDS; overlaps staging latency)
    const float* efp = efeat + eg * 16 + (g & 1) * 8;
    float4 e0 = *(const float4*)efp;
    float4 e1 = *(const float4*)(efp + 4);
    f16x2 ef2[4] = { pkrtz(e0.x, e0.y), pkrtz(e0.z, e0.w),
                     pkrtz(e1.x, e1.y), pkrtz(e1.z, e1.w) };

    __syncthreads();   // drains wct global_load_lds (cross-wave) + h ds_writes

    // h row -> regs; per-s broadcast half2 of h[2s + (g>>1)]
    unsigned int hbc[16];
    f16x8 af_bias;
    {
        const uint4* hrow = (const uint4*)(void*)(h_lds + (wbase + r16) * HROW);
        unsigned int hw[16];
        #pragma unroll
        for (int q = 0; q < 4; ++q) {
            uint4 v = hrow[q];
            hw[q*4+0] = v.x; hw[q*4+1] = v.y; hw[q*4+2] = v.z; hw[q*4+3] = v.w;
        }
        const bool hi = (g >> 1) & 1;
        #pragma unroll
        for (int s = 0; s < 16; ++s) {
            unsigned int x = hi ? (hw[s] >> 16) : (hw[s] & 0xffffu);
            hbc[s] = x | (x << 16);
        }
        af_bias = *(const f16x8*)(void*)((const _Float16*)h_lds + (wbase + r16) * HROW + g * 8);
    }

    const _Float16* brow0 = (const _Float16*)wct_lds + r16 * WCT_ROW;
    const _Float16* brow1 = (const _Float16*)wct_lds + (16 + r16) * WCT_ROW;

    f32x4 acc0 = {0.f, 0.f, 0.f, 0.f};
    f32x4 acc1 = {0.f, 0.f, 0.f, 0.f};

    // X[e,c]=h[i]*ef[kk], c=32s+8g+j => i=2s+(g>>1), kk=(g&1)*8+j
    #pragma unroll
    for (int s = 0; s < 16; ++s) {
        const int koff = s * 32 + g * 8;
        f16x8 b0 = *(const f16x8*)(brow0 + koff);
        f16x8 b1 = *(const f16x8*)(brow1 + koff);
        f16x2 hb = __builtin_bit_cast(f16x2, hbc[s]);
        f16x2 p0 = hb * ef2[0], p1 = hb * ef2[1], p2 = hb * ef2[2], p3 = hb * ef2[3];
        f16x4 lo  = __builtin_shufflevector(p0, p1, 0, 1, 2, 3);
        f16x4 hi4 = __builtin_shufflevector(p2, p3, 0, 1, 2, 3);
        f16x8 af  = __builtin_shufflevector(lo, hi4, 0, 1, 2, 3, 4, 5, 6, 7);
        acc0 = __builtin_amdgcn_mfma_f32_16x16x32_f16(af, b0, acc0, 0, 0, 0);
        acc1 = __builtin_amdgcn_mfma_f32_16x16x32_f16(af, b1, acc1, 0, 0, 0);
    }
    {   // bias-extension k-step: X[e,512+i]=h[i]
        const int koff = 512 + g * 8;
        f16x8 b0 = *(const f16x8*)(brow0 + koff);
        f16x8 b1 = *(const f16x8*)(brow1 + koff);
        acc0 = __builtin_amdgcn_mfma_f32_16x16x32_f16(af_bias, b0, acc0, 0, 0, 0);
        acc1 = __builtin_amdgcn_mfma_f32_16x16x32_f16(af_bias, b1, acc1, 0, 0, 0);
    }

    // D (m89): rows wbase+4g+r (wave-private), cols r16 / 16+r16
    {
        const int browD = wbase + g * 4;
        #pragma unroll
        for (int r = 0; r < 4; ++r) {
            dtile[(browD + r) * DROW + r16]      = acc0[r];
            dtile[(browD + r) * DROW + 16 + r16] = acc1[r];
        }
    }
    // same-wave ds_write -> ds_read fence (rule #18)
    asm volatile("s_waitcnt lgkmcnt(0)" ::: "memory");
    __builtin_amdgcn_sched_barrier(0);

    // Dense f16 msg store (wave-private dtile rows): thread t -> edge et=t>>2,
    // f16 elements (t&3)*8..+8 -> one uint4; wave covers 16 edges x 64B dense.
    {
        const int et = t >> 2, q = t & 3;
        const float* drow = dtile + et * DROW + q * 8;
        f32x4 v0 = *(const f32x4*)(drow);
        f32x4 v1 = *(const f32x4*)(drow + 4);
        uint4 hp;
        hp.x = __builtin_bit_cast(unsigned int, pkrtz(v0[0], v0[1]));
        hp.y = __builtin_bit_cast(unsigned int, pkrtz(v0[2], v0[3]));
        hp.z = __builtin_bit_cast(unsigned int, pkrtz(v1[0], v1[1]));
        hp.w = __builtin_bit_cast(unsigned int, pkrtz(v1[2], v1[3]));
        msgq[(size_t)(ebase + et) * 4 + q] = hp;   // msg[e][32] f16, 64B/edge
    }
}

// ---- D3: pull — 8 lanes per node walk the chain; 64B/edge coalesced f16 reads ----
__global__ __launch_bounds__(256) void pull_kernel(
    const uint2* __restrict__ msg2, const unsigned* __restrict__ head,
    const unsigned* __restrict__ next, const float* __restrict__ bias,
    float* __restrict__ out) {

    int gid = blockIdx.x * 256 + threadIdx.x;
    if (gid >= NNODES * 8) return;
    int n = gid >> 3, Q = gid & 7;

    float4 s = {0.f, 0.f, 0.f, 0.f};
    float degf = 0.0f;

    unsigned e = head[n];
    while (e != 0xFFFFFFFFu) {
        uint2 mw = msg2[(size_t)e * 8 + Q];       // 4 f16 = out chans Q*4..+3
        f16x2 a = __builtin_bit_cast(f16x2, mw.x);
        f16x2 b = __builtin_bit_cast(f16x2, mw.y);
        s.x += (float)a[0]; s.y += (float)a[1];
        s.z += (float)b[0]; s.w += (float)b[1];
        degf += 1.0f;
        e = next[e];
    }

    float inv = 1.0f / fmaxf(degf, 1.0f);
    float4 b = ((const float4*)bias)[Q];
    float4 o = { s.x * inv + b.x, s.y * inv + b.y, s.z * inv + b.z, s.w * inv + b.w };
    *(float4*)(out + n * 32 + Q * 4) = o;
}

extern "C" void kernel_launch(void* const* d_in, const int* in_sizes, int n_in,
                              void* d_out, int out_size, void* d_ws, size_t ws_size,
                              hipStream_t stream) {
    const float* feat   = (const float*)d_in[0];
    const float* efeat  = (const float*)d_in[1];
    const int*   src    = (const int*)d_in[2];
    const int*   dst    = (const int*)d_in[3];
    const float* W_edge = (const float*)d_in[4];
    const float* b_edge = (const float*)d_in[5];
    const float* bias   = (const float*)d_in[6];

    char* ws = (char*)d_ws;
    uint4*    msgq = (uint4*)(ws + MSG_OFF);
    unsigned* head = (unsigned*)(ws + HEAD_OFF);
    unsigned* next = (unsigned*)(ws + NEXT_OFF);
    _Float16* wct  = (_Float16*)(ws + WCT_OFF);
    float*    out  = (float*)d_out;

    init_kernel<<<WCT_BLKS + (NNODES + 255) / 256, 256, 0, stream>>>(
        W_edge, b_edge, wct, head);
    work_kernel<<<NTILES + CHAIN_BLKS, 256, 0, stream>>>(
        feat, efeat, src, dst, wct, msgq, head, next);
    pull_kernel<<<(NNODES * 8 + 255) / 256, 256, 0, stream>>>(
        (const uint2*)msgq, head, next, bias, out);
}

// Round 16
// 40.821 us; speedup vs baseline: 1.1391x; 1.0571x over previous
//
#include <hip/hip_runtime.h>
#include <hip/hip_bf16.h>

#define NNODES 50000
#define NEDGES 200000
#define WCT_ROW 552                      // f16 units; 1104B padded row
#define WCT_BYTES (32 * WCT_ROW * 2)     // 35328
#define HROW 40                          // f16 units; 80B row
#define TILE_EDGES 64
#define NTILES (NEDGES / TILE_EDGES)     // 3125
#define GEMM_BLOCKS ((NTILES + 1) / 2)   // 1563, 2 tiles each
#define CHAIN_BLKS ((NEDGES + 255) / 256) // 782
#define DROW 33                          // dtile row stride (floats)

// workspace layout (bytes, 16B-aligned)
#define MSG_OFF   0                      // f32[200000*32] natural layout msg[e][32]
#define HEAD_OFF  25600000               // u32[50000]
#define NEXT_OFF  25800000               // u32[200000]
#define WCT_OFF   26600000               // f16[32*552]

using f32x4 = __attribute__((ext_vector_type(4))) float;
using f16x2 = __attribute__((ext_vector_type(2))) _Float16;
using f16x4 = __attribute__((ext_vector_type(4))) _Float16;
using f16x8 = __attribute__((ext_vector_type(8))) _Float16;

__device__ __forceinline__ f16x2 pkrtz(float a, float b) {
    return __builtin_bit_cast(f16x2, __builtin_amdgcn_cvt_pkrtz(a, b));
}

__device__ __forceinline__ void gload_lds16(const void* g, void* l) {
    __builtin_amdgcn_global_load_lds(
        (const __attribute__((address_space(1))) unsigned int*)g,
        (__attribute__((address_space(3))) unsigned int*)l, 16, 0, 0);
}

// ---- D1: wct build (blocks 0..68) + head init (blocks 69..) ----
#define WCT_BLKS 69
__global__ void init_kernel(const float* __restrict__ W_edge,
                            const float* __restrict__ b_edge,
                            _Float16* __restrict__ wct,
                            unsigned* __restrict__ head) {
    int b = blockIdx.x;
    if (b < WCT_BLKS) {
        int gid = b * 256 + threadIdx.x;
        if (gid >= 32 * WCT_ROW) return;
        int n = gid / WCT_ROW;
        int c = gid - n * WCT_ROW;
        float v = 0.0f;
        if (c < 512)      v = W_edge[(c & 15) * 1024 + (c >> 4) * 32 + n];
        else if (c < 544) v = b_edge[(c - 512) * 32 + n];
        wct[gid] = (_Float16)v;
    } else {
        int gid = (b - WCT_BLKS) * 256 + threadIdx.x;
        if (gid < NNODES) head[gid] = 0xFFFFFFFFu;
    }
}

// ---- D2: 2-tile pipelined GEMM blocks; chain blocks appended ----
__global__ __launch_bounds__(256, 3) void work_kernel(
    const float* __restrict__ feat, const float* __restrict__ efeat,
    const int* __restrict__ src, const int* __restrict__ dst,
    const _Float16* __restrict__ wct_g,
    float4* __restrict__ msg4, unsigned* __restrict__ head,
    unsigned* __restrict__ next) {

    __shared__ __align__(16) unsigned short wct_lds[32 * WCT_ROW]; // 35328 B
    __shared__ __align__(16) unsigned short h_lds[TILE_EDGES * HROW]; // 5120 B
    __shared__ __align__(16) float dtile[TILE_EDGES * DROW];       // 8448 B

    const int t = threadIdx.x;

    if (blockIdx.x >= GEMM_BLOCKS) {
        // chain-scatter: per-dst linked list via atomicExch (200K atomics)
        int e = (blockIdx.x - GEMM_BLOCKS) * 256 + t;
        if (e < NEDGES)
            next[e] = atomicExch(&head[dst[e]], (unsigned)e);
        return;
    }

    const int lane = t & 63;
    const int wave = t >> 6;
    const int tile0 = blockIdx.x * 2;
    const int tile1 = tile0 + 1;
    const bool has1 = (tile1 < NTILES);
    const int ebase0 = tile0 * TILE_EDGES;
    const int ebase1 = tile1 * TILE_EDGES;

    const int r16 = lane & 15;
    const int g   = lane >> 4;
    const int wbase = wave * 16;
    const int et = t >> 2, p = t & 3;    // staging role: edge et, quarter p

    // Stage WcT global->LDS async (linear dest, 16B/lane)
    {
        const char* gsrc = (const char*)wct_g;
        char* lbase = (char*)wct_lds;
        #pragma unroll
        for (int c = 0; c < 9; ++c) {
            int chunk = wave + c * 4;
            if (chunk < 35) {
                int boff = (chunk << 10) + lane * 16;
                if (boff < WCT_BYTES) gload_lds16(gsrc + boff, lbase + boff);
            }
        }
    }

    // ---- issue-early loads: T0 h-gather, T1 src, T0+T1 ef ----
    const int se0 = src[ebase0 + et];
    int se1 = 0;
    if (has1) se1 = src[ebase1 + et];    // T1 src prefetch (latency hidden)

    float4 ef0a, ef0b, ef1a, ef1b;
    {
        const float* efp = efeat + (ebase0 + wbase + r16) * 16 + (g & 1) * 8;
        ef0a = *(const float4*)efp;
        ef0b = *(const float4*)(efp + 4);
    }
    if (has1) {
        const float* efp = efeat + (ebase1 + wbase + r16) * 16 + (g & 1) * 8;
        ef1a = *(const float4*)efp;
        ef1b = *(const float4*)(efp + 4);
    }

    // T0 h stage (f32 -> f16), wave-private rows
    {
        const float* fp = feat + se0 * 32 + p * 8;
        float4 a = *(const float4*)fp;
        float4 b = *(const float4*)(fp + 4);
        uint4 hp;
        hp.x = __builtin_bit_cast(unsigned int, pkrtz(a.x, a.y));
        hp.y = __builtin_bit_cast(unsigned int, pkrtz(a.z, a.w));
        hp.z = __builtin_bit_cast(unsigned int, pkrtz(b.x, b.y));
        hp.w = __builtin_bit_cast(unsigned int, pkrtz(b.z, b.w));
        *(uint4*)(void*)(h_lds + et * HROW + p * 8) = hp;
    }

    f16x2 ef2[4] = { pkrtz(ef0a.x, ef0a.y), pkrtz(ef0a.z, ef0a.w),
                     pkrtz(ef0b.x, ef0b.y), pkrtz(ef0b.z, ef0b.w) };

    __syncthreads();   // drains wct global_load_lds (cross-wave) + h0 ds_writes

    const _Float16* brow0 = (const _Float16*)wct_lds + r16 * WCT_ROW;
    const _Float16* brow1 = (const _Float16*)wct_lds + (16 + r16) * WCT_ROW;

    // ---- T0: h row -> regs ----
    unsigned int hbc[16];
    f16x8 af_bias;
    {
        const uint4* hrow = (const uint4*)(void*)(h_lds + (wbase + r16) * HROW);
        unsigned int hw[16];
        #pragma unroll
        for (int q = 0; q < 4; ++q) {
            uint4 v = hrow[q];
            hw[q*4+0] = v.x; hw[q*4+1] = v.y; hw[q*4+2] = v.z; hw[q*4+3] = v.w;
        }
        const bool hi = (g >> 1) & 1;
        #pragma unroll
        for (int s = 0; s < 16; ++s) {
            unsigned int x = hi ? (hw[s] >> 16) : (hw[s] & 0xffffu);
            hbc[s] = x | (x << 16);
        }
        af_bias = *(const f16x8*)(void*)((const _Float16*)h_lds + (wbase + r16) * HROW + g * 8);
    }

    // ---- issue T1 feat gather NOW: ~1000cy latency hides under T0 compute ----
    float4 f1a = {0,0,0,0}, f1b = {0,0,0,0};
    if (has1) {
        const float* fp = feat + se1 * 32 + p * 8;
        f1a = *(const float4*)fp;
        f1b = *(const float4*)(fp + 4);
    }

    f32x4 acc0 = {0.f, 0.f, 0.f, 0.f};
    f32x4 acc1 = {0.f, 0.f, 0.f, 0.f};

    // ---- T0 MFMA loop ----
    #pragma unroll
    for (int s = 0; s < 16; ++s) {
        const int koff = s * 32 + g * 8;
        f16x8 b0 = *(const f16x8*)(brow0 + koff);
        f16x8 b1 = *(const f16x8*)(brow1 + koff);
        f16x2 hb = __builtin_bit_cast(f16x2, hbc[s]);
        f16x2 p0 = hb * ef2[0], p1 = hb * ef2[1], p2 = hb * ef2[2], p3 = hb * ef2[3];
        f16x4 lo  = __builtin_shufflevector(p0, p1, 0, 1, 2, 3);
        f16x4 hi4 = __builtin_shufflevector(p2, p3, 0, 1, 2, 3);
        f16x8 af  = __builtin_shufflevector(lo, hi4, 0, 1, 2, 3, 4, 5, 6, 7);
        acc0 = __builtin_amdgcn_mfma_f32_16x16x32_f16(af, b0, acc0, 0, 0, 0);
        acc1 = __builtin_amdgcn_mfma_f32_16x16x32_f16(af, b1, acc1, 0, 0, 0);
    }
    {
        const int koff = 512 + g * 8;
        f16x8 b0 = *(const f16x8*)(brow0 + koff);
        f16x8 b1 = *(const f16x8*)(brow1 + koff);
        acc0 = __builtin_amdgcn_mfma_f32_16x16x32_f16(af_bias, b0, acc0, 0, 0, 0);
        acc1 = __builtin_amdgcn_mfma_f32_16x16x32_f16(af_bias, b1, acc1, 0, 0, 0);
    }

    // T0 D -> dtile (wave-private rows) -> dense msg store
    {
        const int browD = wbase + g * 4;
        #pragma unroll
        for (int r = 0; r < 4; ++r) {
            dtile[(browD + r) * DROW + r16]      = acc0[r];
            dtile[(browD + r) * DROW + 16 + r16] = acc1[r];
        }
    }
    asm volatile("s_waitcnt lgkmcnt(0)" ::: "memory");
    __builtin_amdgcn_sched_barrier(0);
    {
        const int rA = wbase + (lane >> 3);
        const int cA = (lane & 7) * 4;
        float4 vA = *(const float4*)(dtile + rA * DROW + cA);
        float4 vB = *(const float4*)(dtile + (rA + 8) * DROW + cA);
        float4* mp = msg4 + (size_t)ebase0 * 8 + wave * 128;
        mp[lane]      = vA;
        mp[64 + lane] = vB;
    }

    if (!has1) return;

    // ---- T1: stage h (feat already in regs), wave-private; no barrier ----
    {
        uint4 hp;
        hp.x = __builtin_bit_cast(unsigned int, pkrtz(f1a.x, f1a.y));
        hp.y = __builtin_bit_cast(unsigned int, pkrtz(f1a.z, f1a.w));
        hp.z = __builtin_bit_cast(unsigned int, pkrtz(f1b.x, f1b.y));
        hp.w = __builtin_bit_cast(unsigned int, pkrtz(f1b.z, f1b.w));
        *(uint4*)(void*)(h_lds + et * HROW + p * 8) = hp;
    }
    asm volatile("s_waitcnt lgkmcnt(0)" ::: "memory");   // h1 write -> read, same wave
    __builtin_amdgcn_sched_barrier(0);

    ef2[0] = pkrtz(ef1a.x, ef1a.y); ef2[1] = pkrtz(ef1a.z, ef1a.w);
    ef2[2] = pkrtz(ef1b.x, ef1b.y); ef2[3] = pkrtz(ef1b.z, ef1b.w);

    {
        const uint4* hrow = (const uint4*)(void*)(h_lds + (wbase + r16) * HROW);
        unsigned int hw[16];
        #pragma unroll
        for (int q = 0; q < 4; ++q) {
            uint4 v = hrow[q];
            hw[q*4+0] = v.x; hw[q*4+1] = v.y; hw[q*4+2] = v.z; hw[q*4+3] = v.w;
        }
        const bool hi = (g >> 1) & 1;
        #pragma unroll
        for (int s = 0; s < 16; ++s) {
            unsigned int x = hi ? (hw[s] >> 16) : (hw[s] & 0xffffu);
            hbc[s] = x | (x << 16);
        }
        af_bias = *(const f16x8*)(void*)((const _Float16*)h_lds + (wbase + r16) * HROW + g * 8);
    }

    acc0 = (f32x4){0.f, 0.f, 0.f, 0.f};
    acc1 = (f32x4){0.f, 0.f, 0.f, 0.f};

    #pragma unroll
    for (int s = 0; s < 16; ++s) {
        const int koff = s * 32 + g * 8;
        f16x8 b0 = *(const f16x8*)(brow0 + koff);
        f16x8 b1 = *(const f16x8*)(brow1 + koff);
        f16x2 hb = __builtin_bit_cast(f16x2, hbc[s]);
        f16x2 p0 = hb * ef2[0], p1 = hb * ef2[1], p2 = hb * ef2[2], p3 = hb * ef2[3];
        f16x4 lo  = __builtin_shufflevector(p0, p1, 0, 1, 2, 3);
        f16x4 hi4 = __builtin_shufflevector(p2, p3, 0, 1, 2, 3);
        f16x8 af  = __builtin_shufflevector(lo, hi4, 0, 1, 2, 3, 4, 5, 6, 7);
        acc0 = __builtin_amdgcn_mfma_f32_16x16x32_f16(af, b0, acc0, 0, 0, 0);
        acc1 = __builtin_amdgcn_mfma_f32_16x16x32_f16(af, b1, acc1, 0, 0, 0);
    }
    {
        const int koff = 512 + g * 8;
        f16x8 b0 = *(const f16x8*)(brow0 + koff);
        f16x8 b1 = *(const f16x8*)(brow1 + koff);
        acc0 = __builtin_amdgcn_mfma_f32_16x16x32_f16(af_bias, b0, acc0, 0, 0, 0);
        acc1 = __builtin_amdgcn_mfma_f32_16x16x32_f16(af_bias, b1, acc1, 0, 0, 0);
    }

    {
        const int browD = wbase + g * 4;
        #pragma unroll
        for (int r = 0; r < 4; ++r) {
            dtile[(browD + r) * DROW + r16]      = acc0[r];
            dtile[(browD + r) * DROW + 16 + r16] = acc1[r];
        }
    }
    asm volatile("s_waitcnt lgkmcnt(0)" ::: "memory");
    __builtin_amdgcn_sched_barrier(0);
    {
        const int rA = wbase + (lane >> 3);
        const int cA = (lane & 7) * 4;
        float4 vA = *(const float4*)(dtile + rA * DROW + cA);
        float4 vB = *(const float4*)(dtile + (rA + 8) * DROW + cA);
        float4* mp = msg4 + (size_t)ebase1 * 8 + wave * 128;
        mp[lane]      = vA;
        mp[64 + lane] = vB;
    }
}

// ---- D3: pull — 8 lanes per node walk the chain; coalesced 128B/edge reads ----
__global__ __launch_bounds__(256) void pull_kernel(
    const float4* __restrict__ msg4, const unsigned* __restrict__ head,
    const unsigned* __restrict__ next, const float* __restrict__ bias,
    float* __restrict__ out) {

    int gid = blockIdx.x * 256 + threadIdx.x;
    if (gid >= NNODES * 8) return;
    int n = gid >> 3, Q = gid & 7;

    float4 s = {0.f, 0.f, 0.f, 0.f};
    float degf = 0.0f;

    unsigned e = head[n];
    while (e != 0xFFFFFFFFu) {
        float4 m = msg4[(size_t)e * 8 + Q];
        s.x += m.x; s.y += m.y; s.z += m.z; s.w += m.w;
        degf += 1.0f;
        e = next[e];
    }

    float inv = 1.0f / fmaxf(degf, 1.0f);
    float4 b = ((const float4*)bias)[Q];
    float4 o = { s.x * inv + b.x, s.y * inv + b.y, s.z * inv + b.z, s.w * inv + b.w };
    *(float4*)(out + n * 32 + Q * 4) = o;
}

extern "C" void kernel_launch(void* const* d_in, const int* in_sizes, int n_in,
                              void* d_out, int out_size, void* d_ws, size_t ws_size,
                              hipStream_t stream) {
    const float* feat   = (const float*)d_in[0];
    const float* efeat  = (const float*)d_in[1];
    const int*   src    = (const int*)d_in[2];
    const int*   dst    = (const int*)d_in[3];
    const float* W_edge = (const float*)d_in[4];
    const float* b_edge = (const float*)d_in[5];
    const float* bias   = (const float*)d_in[6];

    char* ws = (char*)d_ws;
    float4*   msg4 = (float4*)(ws + MSG_OFF);
    unsigned* head = (unsigned*)(ws + HEAD_OFF);
    unsigned* next = (unsigned*)(ws + NEXT_OFF);
    _Float16* wct  = (_Float16*)(ws + WCT_OFF);
    float*    out  = (float*)d_out;

    init_kernel<<<WCT_BLKS + (NNODES + 255) / 256, 256, 0, stream>>>(
        W_edge, b_edge, wct, head);
    work_kernel<<<GEMM_BLOCKS + CHAIN_BLKS, 256, 0, stream>>>(
        feat, efeat, src, dst, wct, msg4, head, next);
    pull_kernel<<<(NNODES * 8 + 255) / 256, 256, 0, stream>>>(
        msg4, head, next, bias, out);
}